// Round 12
// baseline (91.760 us; speedup 1.0000x reference)
//
#include <hip/hip_runtime.h>
#include <hip/hip_fp16.h>
#include <math.h>

#define NEG_INF_F (-1e30f)
#define LRELU 0.2f

constexpr int Bb = 64, Ee = 512, IND = 1024, OUTD = 256;
constexpr int Mrows = Bb * Ee; // 32768

typedef __attribute__((ext_vector_type(8))) _Float16 half8;
typedef __attribute__((ext_vector_type(4))) _Float16 half4;
typedef __attribute__((ext_vector_type(4))) float floatx4;

#define AS1 __attribute__((address_space(1)))
#define AS3 __attribute__((address_space(3)))

// ---------------- Kernel 0: W fp32 -> fp16 ----------------
__global__ __launch_bounds__(256) void wconv_kernel(
    const float* __restrict__ W, _Float16* __restrict__ Whf)
{
    const int i = (blockIdx.x * 256 + threadIdx.x) * 4;
    const float4 w = *reinterpret_cast<const float4*>(&W[i]);
    half4 hh;
    hh[0] = (_Float16)w.x; hh[1] = (_Float16)w.y;
    hh[2] = (_Float16)w.z; hh[3] = (_Float16)w.w;
    *reinterpret_cast<half4*>(&Whf[i]) = hh;
}

// ---------------- Kernel 1: H = X @ W^T + b (whole-K A in LDS) ----------
// BM=64, BN=256, 512 thr = 8 waves (2x4), wave tile 32x64.
// Phase 1: block loads its 256KB X panel CONTIGUOUSLY (DRAM-page friendly),
//          converts to fp16, stores whole-K A[64][1024] in LDS (128 KB).
// Phase 2: K-loop (32 steps of BK=32) with A from LDS (zero HBM) and B
//          (L2-resident Whf) double-buffered via global_load_lds (32 KB).
// LDS = 160 KB exactly -> 1 block/CU; grid 512 = 2 rounds.
__global__ __launch_bounds__(512, 1) void gemm_h_f16(
    const float* __restrict__ X, const _Float16* __restrict__ Whf,
    const float* __restrict__ Wb, const float* __restrict__ aw,
    const int* __restrict__ mask,
    _Float16* __restrict__ HmTh, float* __restrict__ s1, float* __restrict__ s2)
{
    __shared__ char lds_raw[163840];
    _Float16* Ah = (_Float16*)lds_raw;              // [64][1024] fp16, 128 KB
    _Float16* Bf = (_Float16*)(lds_raw + 131072);   // [2][256][32] fp16, 32 KB
    // epilogue overlays:
    _Float16* Th   = (_Float16*)(lds_raw + 131072); // [256][64] 32 KB (over Bf)
    float*    s1p  = (float*)lds_raw;               // [8][32] (over Ah)
    float*    s2p  = (float*)(lds_raw + 1024);
    float*    mkfs = (float*)(lds_raw + 2048);      // [64]

    const int t  = threadIdx.x;
    const int w  = t >> 6, l = t & 63, ln = l & 15, lg = l >> 4;
    const int wr = w >> 2, wc = w & 3;   // 2 x 4 wave grid
    const int m0 = blockIdx.x * 64;

    // B stage mapping (r6-proven): 2 instrs/wave, 16 rows each, pre-swizzled src
    const int brl = l >> 2;                   // row within 16-row group
    const int bgl = (l & 3) ^ ((l >> 3) & 3); // pre-swizzled source granule

    auto stageB = [&](int kc, int boff) {
        #pragma unroll
        for (int i = 0; i < 2; ++i) {
            const int nbase = w * 32 + i * 16;
            const size_t src = (size_t)(nbase + brl) * IND + kc * 32 + bgl * 8;
            __builtin_amdgcn_global_load_lds(
                (const AS1 unsigned int*)(Whf + src),
                (AS3 unsigned int*)(Bf + boff + nbase * 32), 16, 0, 0);
        }
    };

    // issue B(k0) DMA early; it completes during phase 1
    stageB(0, 0);

    // ---- phase 1: contiguous X panel load + fp16 convert into LDS ----
    {
        const int prow = w * 8 + (l >> 3);   // wave covers 8 rows
        const int ps   = l & 7;
        const float* __restrict__ xsrc = X + (size_t)(m0 + prow) * IND + ps * 8;
        _Float16* __restrict__ adst = Ah + prow * 1024;
        #pragma unroll 4
        for (int ii = 0; ii < 16; ++ii) {
            const float4 u0 = *reinterpret_cast<const float4*>(xsrc + ii * 64);
            const float4 u1 = *reinterpret_cast<const float4*>(xsrc + ii * 64 + 4);
            half8 h;
            h[0] = (_Float16)u0.x; h[1] = (_Float16)u0.y;
            h[2] = (_Float16)u0.z; h[3] = (_Float16)u0.w;
            h[4] = (_Float16)u1.x; h[5] = (_Float16)u1.y;
            h[6] = (_Float16)u1.z; h[7] = (_Float16)u1.w;
            const int phys = ii * 8 + (ps ^ (prow & 7));
            *reinterpret_cast<half8*>(adst + phys * 8) = h;
        }
    }
    __syncthreads();   // A resident; B(k0) also drained by the implicit waits

    floatx4 acc[2][4];
    #pragma unroll
    for (int i = 0; i < 2; ++i)
        #pragma unroll
        for (int j = 0; j < 4; ++j)
            acc[i][j] = (floatx4)0.f;

    // ---- phase 2: K-loop, A from LDS, B double-buffered from L2 ----
    for (int ts = 0; ts < 32; ++ts) {
        const int cur = (ts & 1) * 8192;
        if (ts < 31) stageB(ts + 1, 8192 - cur);
        __builtin_amdgcn_sched_barrier(0);

        half8 bfrag[4];
        #pragma unroll
        for (int nr = 0; nr < 4; ++nr) {
            const int n = wc * 64 + nr * 16 + ln;
            const int phys = lg ^ ((n >> 1) & 3);
            bfrag[nr] = *reinterpret_cast<const half8*>(Bf + cur + n * 32 + phys * 8);
        }
        half8 afrag[2];
        #pragma unroll
        for (int mr = 0; mr < 2; ++mr) {
            const int r = wr * 32 + mr * 16 + ln;
            const int gphys = (ts >> 1) * 8 + (((ts & 1) * 4 + lg) ^ (r & 7));
            afrag[mr] = *reinterpret_cast<const half8*>(Ah + r * 1024 + gphys * 8);
        }

        __builtin_amdgcn_s_setprio(1);
        #pragma unroll
        for (int mr = 0; mr < 2; ++mr)
            #pragma unroll
            for (int nr = 0; nr < 4; ++nr)
                acc[mr][nr] = __builtin_amdgcn_mfma_f32_16x16x32_f16(
                    afrag[mr], bfrag[nr], acc[mr][nr], 0, 0, 0);
        __builtin_amdgcn_s_setprio(0);

        asm volatile("s_waitcnt vmcnt(0) lgkmcnt(0)" ::: "memory");
        __builtin_amdgcn_sched_barrier(0);
        __builtin_amdgcn_s_barrier();
        __builtin_amdgcn_sched_barrier(0);
    }

    // ---- epilogue (8-wave, wave tile 32x64; r10-proven) ----
    if (t < 64) mkfs[t] = (float)mask[m0 + t];

    float bias[4], a1c[4], a2c[4];
    #pragma unroll
    for (int nr = 0; nr < 4; ++nr) {
        const int n = wc * 64 + nr * 16 + ln;
        bias[nr] = Wb[n];
        a1c[nr]  = aw[n];
        a2c[nr]  = aw[OUTD + n];
    }
    float sv1[2][4], sv2[2][4];
    #pragma unroll
    for (int i = 0; i < 2; ++i)
        #pragma unroll
        for (int r = 0; r < 4; ++r) { sv1[i][r] = 0.f; sv2[i][r] = 0.f; }

    #pragma unroll
    for (int mr = 0; mr < 2; ++mr)
        #pragma unroll
        for (int nr = 0; nr < 4; ++nr) {
            const int o = wc * 64 + nr * 16 + ln;
            half4 hh;
            #pragma unroll
            for (int rr = 0; rr < 4; ++rr) {
                const float hb = acc[mr][nr][rr] + bias[nr];
                sv1[mr][rr] += hb * a1c[nr];
                sv2[mr][rr] += hb * a2c[nr];
                hh[rr] = (_Float16)hb;
            }
            const int e = wr * 32 + mr * 16 + lg * 4;
            *reinterpret_cast<half4*>(Th + o * 64 + (e ^ ((o & 7) << 3))) = hh;
        }

    #pragma unroll
    for (int mr = 0; mr < 2; ++mr)
        #pragma unroll
        for (int rr = 0; rr < 4; ++rr) {
            float v1 = sv1[mr][rr], v2 = sv2[mr][rr];
            #pragma unroll
            for (int off = 1; off < 16; off <<= 1) {
                v1 += __shfl_xor(v1, off, 64);
                v2 += __shfl_xor(v2, off, 64);
            }
            if (ln == 0) {
                const int el = mr * 16 + lg * 4 + rr;   // 0..31
                s1p[w * 32 + el] = v1;
                s2p[w * 32 + el] = v2;
            }
        }
    __syncthreads();

    if (t < 64) {
        const int wrr = t >> 5, el = t & 31;
        const int b0 = (wrr * 4) * 32 + el;
        s1[m0 + t] = s1p[b0] + s1p[b0 + 32] + s1p[b0 + 64] + s1p[b0 + 96];
        s2[m0 + t] = s2p[b0] + s2p[b0 + 32] + s2p[b0 + 64] + s2p[b0 + 96];
    }

    // coalesced masked HmT store
    const int bIdx = m0 >> 9;
    const int e0   = m0 & 511;
    const int e4   = (t & 15) * 4;
    const float q0 = mkfs[e4 + 0], q1 = mkfs[e4 + 1];
    const float q2 = mkfs[e4 + 2], q3 = mkfs[e4 + 3];
    #pragma unroll
    for (int it = 0; it < 8; ++it) {
        const int o = it * 32 + (t >> 4);
        half4 vh = *reinterpret_cast<const half4*>(Th + o * 64 + (e4 ^ ((o & 7) << 3)));
        if (!(q0 > 0.f)) vh[0] = (_Float16)0.f;
        if (!(q1 > 0.f)) vh[1] = (_Float16)0.f;
        if (!(q2 > 0.f)) vh[2] = (_Float16)0.f;
        if (!(q3 > 0.f)) vh[3] = (_Float16)0.f;
        const size_t goff = ((size_t)(bIdx * OUTD + o) << 9) + e0 + e4;
        *reinterpret_cast<half4*>(&HmTh[goff]) = vh;
    }
}

// ---------------- Kernel 2: out[b] = softmax(scores[b]) @ (H[b]*m), MFMA ----
__global__ __launch_bounds__(256, 2) void attn_mfma(
    const _Float16* __restrict__ HmTh,
    const float* __restrict__ s1, const float* __restrict__ s2,
    const int* __restrict__ mask, const float* __restrict__ ab_ptr,
    float* __restrict__ Out)
{
    __shared__ float s2v[Ee];
    __shared__ float mkv[Ee];
    __shared__ float rowc[64];
    __shared__ float rmax[64];
    __shared__ int   rvv[64];
    __shared__ _Float16 Pl[2][64][32];
    __shared__ float Zp[64][4];
    __shared__ float zr[64];
    __shared__ float wmax[4];

    const int bid = blockIdx.x;
    const int b  = bid & 63;
    const int i0 = (bid >> 6) * 64;
    const int t  = threadIdx.x;
    const int w  = t >> 6, l = t & 63, ln = l & 15, lg = l >> 4;
    const float ab = ab_ptr[0];

    float lmax = -INFINITY;
    #pragma unroll
    for (int q = 0; q < 2; ++q) {
        const int j = t + q * 256;
        const float sv = s2[b * Ee + j];
        const float mv = (float)mask[b * Ee + j];
        s2v[j] = sv; mkv[j] = mv;
        if (mv > 0.f) lmax = fmaxf(lmax, sv);
    }
    #pragma unroll
    for (int off = 32; off; off >>= 1) lmax = fmaxf(lmax, __shfl_xor(lmax, off, 64));
    if (l == 0) wmax[w] = lmax;
    __syncthreads();
    const float s2max = fmaxf(fmaxf(wmax[0], wmax[1]), fmaxf(wmax[2], wmax[3]));
    const int anyvalid = (s2max > -1e37f) ? 1 : 0;
    if (t < 64) {
        const float c = s1[b * Ee + i0 + t] + ab;
        rowc[t] = c;
        const int mi = mask[b * Ee + i0 + t];
        rvv[t] = (mi != 0) & anyvalid;
        const float rm = c + s2max;
        rmax[t] = (rm >= 0.f) ? rm : LRELU * rm;
    }
    __syncthreads();

    const int pi = t >> 2;
    const int pj = (t & 3) * 8;
    const float prc = rowc[pi];
    const float prm = rmax[pi];
    const int   prv = rvv[pi];
    float zacc = 0.f;

    const size_t obase = (size_t)b * OUTD * Ee;
    const int o0 = w * 64;

    floatx4 acc[4][4];
    #pragma unroll
    for (int i = 0; i < 4; ++i)
        #pragma unroll
        for (int j = 0; j < 4; ++j)
            acc[i][j] = (floatx4)0.f;

    for (int ks = 0; ks < 16; ++ks) {
        const int k0  = ks * 32;
        const int buf = ks & 1;

        half8 ph;
        #pragma unroll
        for (int kk = 0; kk < 8; ++kk) {
            const int j = k0 + pj + kk;
            float pv;
            if (prv) {
                float sc = prc + s2v[j];
                sc = (sc >= 0.f) ? sc : LRELU * sc;
                pv = (mkv[j] > 0.f) ? __expf(sc - prm) : 0.f;
            } else {
                pv = 1.f;
            }
            const _Float16 hq = (_Float16)pv;
            ph[kk] = hq;
            zacc += (float)hq;
        }
        *reinterpret_cast<half8*>(&Pl[buf][pi][pj]) = ph;

        half8 bh[4];
        #pragma unroll
        for (int ot = 0; ot < 4; ++ot) {
            const size_t ro = obase + (size_t)(o0 + ot * 16 + ln) * Ee + k0 + lg * 8;
            bh[ot] = *reinterpret_cast<const half8*>(&HmTh[ro]);
        }
        __syncthreads();

        half8 af[4];
        #pragma unroll
        for (int mr = 0; mr < 4; ++mr)
            af[mr] = *reinterpret_cast<const half8*>(&Pl[buf][mr * 16 + ln][lg * 8]);
        #pragma unroll
        for (int mr = 0; mr < 4; ++mr)
            #pragma unroll
            for (int ot = 0; ot < 4; ++ot)
                acc[mr][ot] = __builtin_amdgcn_mfma_f32_16x16x32_f16(
                    af[mr], bh[ot], acc[mr][ot], 0, 0, 0);
    }

    Zp[pi][t & 3] = zacc;
    __syncthreads();
    if (t < 64) {
        const float z = Zp[t][0] + Zp[t][1] + Zp[t][2] + Zp[t][3];
        zr[t] = 1.f / z;
    }
    __syncthreads();

    float* __restrict__ Ob = Out + ((size_t)b * Ee + i0) * OUTD;
    #pragma unroll
    for (int mr = 0; mr < 4; ++mr)
        #pragma unroll
        for (int rr = 0; rr < 4; ++rr) {
            const int i = mr * 16 + lg * 4 + rr;
            const float rzi = zr[i];
            #pragma unroll
            for (int ot = 0; ot < 4; ++ot)
                Ob[(size_t)i * OUTD + o0 + ot * 16 + ln] = acc[mr][ot][rr] * rzi;
        }
}

extern "C" void kernel_launch(void* const* d_in, const int* in_sizes, int n_in,
                              void* d_out, int out_size, void* d_ws, size_t ws_size,
                              hipStream_t stream) {
    const float* X    = (const float*)d_in[0];
    // d_in[1] = adj : unused by the reference (dead input)
    const int*   mask = (const int*)d_in[2];
    const float* Ww   = (const float*)d_in[3];
    const float* Wb   = (const float*)d_in[4];
    const float* aw   = (const float*)d_in[5];
    const float* ab   = (const float*)d_in[6];
    float* out = (float*)d_out;

    _Float16* HmTh = (_Float16*)d_ws;                     // [64][256][512] fp16 = 16 MB
    float* s1 = (float*)(HmTh + (size_t)Bb * OUTD * Ee);  // 128 KB
    float* s2 = s1 + Mrows;                               // 128 KB
    _Float16* Whf = (_Float16*)(s2 + Mrows);              // 512 KB

    wconv_kernel<<<OUTD * IND / (256 * 4), 256, 0, stream>>>(Ww, Whf);
    gemm_h_f16<<<Mrows / 64, 512, 0, stream>>>(X, Whf, Wb, aw, mask, HmTh, s1, s2);
    attn_mfma<<<Bb * (Ee / 64), 256, 0, stream>>>(HmTh, s1, s2, mask, ab, out);
}

// Round 13
// 69.708 us; speedup vs baseline: 1.3163x; 1.3163x over previous
//
#include <hip/hip_runtime.h>
#include <hip/hip_fp16.h>
#include <math.h>

#define NEG_INF_F (-1e30f)
#define LRELU 0.2f

constexpr int Bb = 64, Ee = 512, IND = 1024, OUTD = 256;
constexpr int Mrows = Bb * Ee; // 32768

typedef __attribute__((ext_vector_type(8))) _Float16 half8;
typedef __attribute__((ext_vector_type(4))) _Float16 half4;
typedef __attribute__((ext_vector_type(4))) float floatx4;

#define AS1 __attribute__((address_space(1)))
#define AS3 __attribute__((address_space(3)))

// ---------------- Kernel 0: W fp32 -> fp16 ----------------
__global__ __launch_bounds__(256) void wconv_kernel(
    const float* __restrict__ W, _Float16* __restrict__ Whf)
{
    const int i = (blockIdx.x * 256 + threadIdx.x) * 4;
    const float4 w = *reinterpret_cast<const float4*>(&W[i]);
    half4 hh;
    hh[0] = (_Float16)w.x; hh[1] = (_Float16)w.y;
    hh[2] = (_Float16)w.z; hh[3] = (_Float16)w.w;
    *reinterpret_cast<half4*>(&Whf[i]) = hh;
}

// ---------------- Kernel 1: H = X @ W^T + b ----------------
// r8 structure (best measured) + depth-3 prefetch: BM=128, BN=256, BK=32,
// 512 thr = 8 waves (2x4), wave tile 64x64. ALL staging via global_load_lds
// (A raw fp32, converted at frag build; B fp16). FOUR buffers, 3 tranches
// (12 VMEM instrs/wave, 96 KB/CU) in flight across barriers; steady-state
// wait vmcnt(8). 256 blocks = 1/CU.
__global__ __launch_bounds__(512, 2) void gemm_h_f16(
    const float* __restrict__ X, const _Float16* __restrict__ Whf,
    const float* __restrict__ Wb, const float* __restrict__ aw,
    const int* __restrict__ mask,
    _Float16* __restrict__ HmTh, float* __restrict__ s1, float* __restrict__ s2)
{
    __shared__ char lds_raw[131072];
    float*    Af  = (float*)lds_raw;               // [4][128][32] fp32, 64 KB
    _Float16* Bf  = (_Float16*)(lds_raw + 65536);  // [4][256][32] fp16, 64 KB
    // epilogue overlays:
    _Float16* Th   = (_Float16*)lds_raw;           // [256][128] 64 KB
    float*    s1p  = (float*)(lds_raw + 65536);    // [4][128]
    float*    s2p  = (float*)(lds_raw + 67584);    // [4][128]
    float*    mkfs = (float*)(lds_raw + 69632);    // [128]

    const int t  = threadIdx.x;
    const int w  = t >> 6, l = t & 63, ln = l & 15, lg = l >> 4;
    const int wr = w >> 2, wc = w & 3;
    const int m0 = blockIdx.x * 128;

    // A stage: 2 instrs/wave, instr i covers rows w*16 + i*8 .. +8 (1 KB each).
    const int arl = l >> 3;                   // row within 8-row group
    const int agl = (l & 7) ^ arl;            // pre-swizzled source granule (4 fp32)
    // B stage: 2 instrs/wave, instr i covers rows w*32 + i*16 .. +16 (1 KB each).
    const int brl = l >> 2;                   // row within 16-row group
    const int bgl = (l & 3) ^ ((l >> 3) & 3); // pre-swizzled source granule (8 halves)

    floatx4 acc[4][4];
    #pragma unroll
    for (int i = 0; i < 4; ++i)
        #pragma unroll
        for (int j = 0; j < 4; ++j)
            acc[i][j] = (floatx4)0.f;

    auto stageA = [&](int kc, int slot) {
        #pragma unroll
        for (int i = 0; i < 2; ++i) {
            const int rbase = w * 16 + i * 8;
            const size_t src = (size_t)(m0 + rbase + arl) * IND + kc * 32 + agl * 4;
            __builtin_amdgcn_global_load_lds(
                (const AS1 unsigned int*)(X + src),
                (AS3 unsigned int*)(Af + slot * 4096 + rbase * 32), 16, 0, 0);
        }
    };
    auto stageB = [&](int kc, int slot) {
        #pragma unroll
        for (int i = 0; i < 2; ++i) {
            const int nbase = w * 32 + i * 16;
            const size_t src = (size_t)(nbase + brl) * IND + kc * 32 + bgl * 8;
            __builtin_amdgcn_global_load_lds(
                (const AS1 unsigned int*)(Whf + src),
                (AS3 unsigned int*)(Bf + slot * 8192 + nbase * 32), 16, 0, 0);
        }
    };

    // ---- prologue: 3 tranches in flight ----
    stageA(0, 0); stageB(0, 0);
    stageA(1, 1); stageB(1, 1);
    stageA(2, 2); stageB(2, 2);
    asm volatile("s_waitcnt vmcnt(8) lgkmcnt(0)" ::: "memory"); // tranche 0 done
    __builtin_amdgcn_sched_barrier(0);
    __builtin_amdgcn_s_barrier();
    __builtin_amdgcn_sched_barrier(0);

    for (int ts = 0; ts < 32; ++ts) {
        const int cur = ts & 3;
        if (ts < 29) { stageA(ts + 3, (ts + 3) & 3); stageB(ts + 3, (ts + 3) & 3); }
        __builtin_amdgcn_sched_barrier(0);

        // ---- fragments from slot cur ----
        half8 bfrag[4];
        #pragma unroll
        for (int nr = 0; nr < 4; ++nr) {
            const int n = wc * 64 + nr * 16 + ln;
            const int phys = lg ^ ((n >> 1) & 3);
            bfrag[nr] = *reinterpret_cast<const half8*>(Bf + cur * 8192 + n * 32 + phys * 8);
        }
        half8 afrag[4];
        #pragma unroll
        for (int mr = 0; mr < 4; ++mr) {
            const int r = wr * 64 + mr * 16 + ln;
            const int g0 = (lg * 2) ^ (r & 7);
            const int g1 = (lg * 2 + 1) ^ (r & 7);
            const floatx4 a0 = *reinterpret_cast<const floatx4*>(Af + cur * 4096 + r * 32 + g0 * 4);
            const floatx4 a1 = *reinterpret_cast<const floatx4*>(Af + cur * 4096 + r * 32 + g1 * 4);
            half8 h;
            h[0] = (_Float16)a0[0]; h[1] = (_Float16)a0[1];
            h[2] = (_Float16)a0[2]; h[3] = (_Float16)a0[3];
            h[4] = (_Float16)a1[0]; h[5] = (_Float16)a1[1];
            h[6] = (_Float16)a1[2]; h[7] = (_Float16)a1[3];
            afrag[mr] = h;
        }

        __builtin_amdgcn_s_setprio(1);
        #pragma unroll
        for (int mr = 0; mr < 4; ++mr)
            #pragma unroll
            for (int nr = 0; nr < 4; ++nr)
                acc[mr][nr] = __builtin_amdgcn_mfma_f32_16x16x32_f16(
                    afrag[mr], bfrag[nr], acc[mr][nr], 0, 0, 0);
        __builtin_amdgcn_s_setprio(0);

        // counted wait: next tranche complete, 2 more stay in flight
        if (ts < 29)      asm volatile("s_waitcnt vmcnt(8) lgkmcnt(0)" ::: "memory");
        else if (ts == 29) asm volatile("s_waitcnt vmcnt(4) lgkmcnt(0)" ::: "memory");
        else              asm volatile("s_waitcnt vmcnt(0) lgkmcnt(0)" ::: "memory");
        __builtin_amdgcn_sched_barrier(0);
        __builtin_amdgcn_s_barrier();
        __builtin_amdgcn_sched_barrier(0);
    }

    // ---- epilogue (r8-proven) ----
    if (t < 128) mkfs[t] = (float)mask[m0 + t];

    float bias[4], a1c[4], a2c[4];
    #pragma unroll
    for (int nr = 0; nr < 4; ++nr) {
        const int n = wc * 64 + nr * 16 + ln;
        bias[nr] = Wb[n];
        a1c[nr]  = aw[n];
        a2c[nr]  = aw[OUTD + n];
    }
    float sv1[4][4], sv2[4][4];
    #pragma unroll
    for (int i = 0; i < 4; ++i)
        #pragma unroll
        for (int r = 0; r < 4; ++r) { sv1[i][r] = 0.f; sv2[i][r] = 0.f; }

    #pragma unroll
    for (int mr = 0; mr < 4; ++mr)
        #pragma unroll
        for (int nr = 0; nr < 4; ++nr) {
            const int o = wc * 64 + nr * 16 + ln;
            half4 hh;
            #pragma unroll
            for (int rr = 0; rr < 4; ++rr) {
                const float hb = acc[mr][nr][rr] + bias[nr];
                sv1[mr][rr] += hb * a1c[nr];
                sv2[mr][rr] += hb * a2c[nr];
                hh[rr] = (_Float16)hb;
            }
            const int e = wr * 64 + mr * 16 + lg * 4;
            *reinterpret_cast<half4*>(Th + o * 128 + (e ^ ((o & 7) << 3))) = hh;
        }

    #pragma unroll
    for (int mr = 0; mr < 4; ++mr)
        #pragma unroll
        for (int rr = 0; rr < 4; ++rr) {
            float v1 = sv1[mr][rr], v2 = sv2[mr][rr];
            #pragma unroll
            for (int off = 1; off < 16; off <<= 1) {
                v1 += __shfl_xor(v1, off, 64);
                v2 += __shfl_xor(v2, off, 64);
            }
            if (ln == 0) {
                const int e = wr * 64 + mr * 16 + lg * 4 + rr;
                s1p[wc * 128 + e] = v1;
                s2p[wc * 128 + e] = v2;
            }
        }
    __syncthreads();

    if (t < 128) {
        s1[m0 + t] = s1p[t] + s1p[128 + t] + s1p[256 + t] + s1p[384 + t];
        s2[m0 + t] = s2p[t] + s2p[128 + t] + s2p[256 + t] + s2p[384 + t];
    }

    // coalesced masked HmT store: 256B contiguous per o-row
    const int bIdx = m0 >> 9;
    const int e0   = m0 & 511;
    const int e4   = (t & 31) * 4;
    const float q0 = mkfs[e4 + 0], q1 = mkfs[e4 + 1];
    const float q2 = mkfs[e4 + 2], q3 = mkfs[e4 + 3];
    #pragma unroll
    for (int it = 0; it < 16; ++it) {
        const int o = it * 16 + (t >> 5);
        half4 vh = *reinterpret_cast<const half4*>(Th + o * 128 + (e4 ^ ((o & 7) << 3)));
        if (!(q0 > 0.f)) vh[0] = (_Float16)0.f;
        if (!(q1 > 0.f)) vh[1] = (_Float16)0.f;
        if (!(q2 > 0.f)) vh[2] = (_Float16)0.f;
        if (!(q3 > 0.f)) vh[3] = (_Float16)0.f;
        const size_t goff = ((size_t)(bIdx * OUTD + o) << 9) + e0 + e4;
        *reinterpret_cast<half4*>(&HmTh[goff]) = vh;
    }
}

// ---------------- Kernel 2: out[b] = softmax(scores[b]) @ (H[b]*m), MFMA ----
__global__ __launch_bounds__(256, 2) void attn_mfma(
    const _Float16* __restrict__ HmTh,
    const float* __restrict__ s1, const float* __restrict__ s2,
    const int* __restrict__ mask, const float* __restrict__ ab_ptr,
    float* __restrict__ Out)
{
    __shared__ float s2v[Ee];
    __shared__ float mkv[Ee];
    __shared__ float rowc[64];
    __shared__ float rmax[64];
    __shared__ int   rvv[64];
    __shared__ _Float16 Pl[2][64][32];
    __shared__ float Zp[64][4];
    __shared__ float zr[64];
    __shared__ float wmax[4];

    const int bid = blockIdx.x;
    const int b  = bid & 63;
    const int i0 = (bid >> 6) * 64;
    const int t  = threadIdx.x;
    const int w  = t >> 6, l = t & 63, ln = l & 15, lg = l >> 4;
    const float ab = ab_ptr[0];

    float lmax = -INFINITY;
    #pragma unroll
    for (int q = 0; q < 2; ++q) {
        const int j = t + q * 256;
        const float sv = s2[b * Ee + j];
        const float mv = (float)mask[b * Ee + j];
        s2v[j] = sv; mkv[j] = mv;
        if (mv > 0.f) lmax = fmaxf(lmax, sv);
    }
    #pragma unroll
    for (int off = 32; off; off >>= 1) lmax = fmaxf(lmax, __shfl_xor(lmax, off, 64));
    if (l == 0) wmax[w] = lmax;
    __syncthreads();
    const float s2max = fmaxf(fmaxf(wmax[0], wmax[1]), fmaxf(wmax[2], wmax[3]));
    const int anyvalid = (s2max > -1e37f) ? 1 : 0;
    if (t < 64) {
        const float c = s1[b * Ee + i0 + t] + ab;
        rowc[t] = c;
        const int mi = mask[b * Ee + i0 + t];
        rvv[t] = (mi != 0) & anyvalid;
        const float rm = c + s2max;
        rmax[t] = (rm >= 0.f) ? rm : LRELU * rm;
    }
    __syncthreads();

    const int pi = t >> 2;
    const int pj = (t & 3) * 8;
    const float prc = rowc[pi];
    const float prm = rmax[pi];
    const int   prv = rvv[pi];
    float zacc = 0.f;

    const size_t obase = (size_t)b * OUTD * Ee;
    const int o0 = w * 64;

    floatx4 acc[4][4];
    #pragma unroll
    for (int i = 0; i < 4; ++i)
        #pragma unroll
        for (int j = 0; j < 4; ++j)
            acc[i][j] = (floatx4)0.f;

    for (int ks = 0; ks < 16; ++ks) {
        const int k0  = ks * 32;
        const int buf = ks & 1;

        half8 ph;
        #pragma unroll
        for (int kk = 0; kk < 8; ++kk) {
            const int j = k0 + pj + kk;
            float pv;
            if (prv) {
                float sc = prc + s2v[j];
                sc = (sc >= 0.f) ? sc : LRELU * sc;
                pv = (mkv[j] > 0.f) ? __expf(sc - prm) : 0.f;
            } else {
                pv = 1.f;
            }
            const _Float16 hq = (_Float16)pv;
            ph[kk] = hq;
            zacc += (float)hq;
        }
        *reinterpret_cast<half8*>(&Pl[buf][pi][pj]) = ph;

        half8 bh[4];
        #pragma unroll
        for (int ot = 0; ot < 4; ++ot) {
            const size_t ro = obase + (size_t)(o0 + ot * 16 + ln) * Ee + k0 + lg * 8;
            bh[ot] = *reinterpret_cast<const half8*>(&HmTh[ro]);
        }
        __syncthreads();

        half8 af[4];
        #pragma unroll
        for (int mr = 0; mr < 4; ++mr)
            af[mr] = *reinterpret_cast<const half8*>(&Pl[buf][mr * 16 + ln][lg * 8]);
        #pragma unroll
        for (int mr = 0; mr < 4; ++mr)
            #pragma unroll
            for (int ot = 0; ot < 4; ++ot)
                acc[mr][ot] = __builtin_amdgcn_mfma_f32_16x16x32_f16(
                    af[mr], bh[ot], acc[mr][ot], 0, 0, 0);
    }

    Zp[pi][t & 3] = zacc;
    __syncthreads();
    if (t < 64) {
        const float z = Zp[t][0] + Zp[t][1] + Zp[t][2] + Zp[t][3];
        zr[t] = 1.f / z;
    }
    __syncthreads();

    float* __restrict__ Ob = Out + ((size_t)b * Ee + i0) * OUTD;
    #pragma unroll
    for (int mr = 0; mr < 4; ++mr)
        #pragma unroll
        for (int rr = 0; rr < 4; ++rr) {
            const int i = mr * 16 + lg * 4 + rr;
            const float rzi = zr[i];
            #pragma unroll
            for (int ot = 0; ot < 4; ++ot)
                Ob[(size_t)i * OUTD + o0 + ot * 16 + ln] = acc[mr][ot][rr] * rzi;
        }
}

extern "C" void kernel_launch(void* const* d_in, const int* in_sizes, int n_in,
                              void* d_out, int out_size, void* d_ws, size_t ws_size,
                              hipStream_t stream) {
    const float* X    = (const float*)d_in[0];
    // d_in[1] = adj : unused by the reference (dead input)
    const int*   mask = (const int*)d_in[2];
    const float* Ww   = (const float*)d_in[3];
    const float* Wb   = (const float*)d_in[4];
    const float* aw   = (const float*)d_in[5];
    const float* ab   = (const float*)d_in[6];
    float* out = (float*)d_out;

    _Float16* HmTh = (_Float16*)d_ws;                     // [64][256][512] fp16 = 16 MB
    float* s1 = (float*)(HmTh + (size_t)Bb * OUTD * Ee);  // 128 KB
    float* s2 = s1 + Mrows;                               // 128 KB
    _Float16* Whf = (_Float16*)(s2 + Mrows);              // 512 KB

    wconv_kernel<<<OUTD * IND / (256 * 4), 256, 0, stream>>>(Ww, Whf);
    gemm_h_f16<<<Mrows / 128, 512, 0, stream>>>(X, Whf, Wb, aw, mask, HmTh, s1, s2);
    attn_mfma<<<Bb * (Ee / 64), 256, 0, stream>>>(HmTh, s1, s2, mask, ab, out);
}